// Round 8
// baseline (170.893 us; speedup 1.0000x reference)
//
#include <hip/hip_runtime.h>

// Frames [B, T, C, H, W] = [8, 8, 3, 256, 256] fp32
#define BB 8
#define TT 8
#define NPAIR (TT - 1)               // 7
#define HH 256
#define WW 256
#define FRAME_PIX (HH * WW)
#define RROWS 4                      // rows per wave-item
#define NSTRIP (HH / RROWS)          // 64 strips per frame pair
#define NITEM (BB * NPAIR * NSTRIP)  // 3584 wave items
#define NBLK (NITEM / 2)             // 1792 blocks x 2 waves (128 thr)
#define EPS 1e-3f
#define INV_N (1.0f / (float)((size_t)BB * NPAIR * 2 * HH * WW))

__device__ __forceinline__ float4 ld4(const float* __restrict__ p) {
    return *reinterpret_cast<const float4*>(p);
}
__device__ __forceinline__ float4 gray4(const float4 r, const float4 g, const float4 b) {
    float4 o;
    o.x = 0.2989f * r.x + 0.587f * g.x + 0.114f * b.x;
    o.y = 0.2989f * r.y + 0.587f * g.y + 0.114f * b.y;
    o.z = 0.2989f * r.z + 0.587f * g.z + 0.114f * b.z;
    o.w = 0.2989f * r.w + 0.587f * g.w + 0.114f * b.w;
    return o;
}

// One gray row per lane: 4 center px (a..d) + left/right halo from neighbor
// lanes via shuffle. NAMED FIELDS ONLY - never array-indexed (round-5
// lesson: indexed arrays were demoted to scratch).
struct GRow { float l, a, b, c, d, r; };

__device__ __forceinline__ GRow mk_grow(const float4 g, const int lane) {
    GRow o;
    o.a = g.x; o.b = g.y; o.c = g.z; o.d = g.w;
    const float lw = __shfl_up(g.w, 1, 64);
    const float rx = __shfl_down(g.x, 1, 64);
    o.l = (lane == 0) ? 0.f : lw;
    o.r = (lane == 63) ? 0.f : rx;
    return o;
}

// Load 3 channels of one row (4 px per lane); wave-uniform validity check
// implements the conv zero padding for rows outside the image.
__device__ __forceinline__ void ld3(const float* __restrict__ base, const int y,
                                    const int X, float4& c0, float4& c1, float4& c2) {
    if ((unsigned)y < (unsigned)HH) {
        const float* q = base + (size_t)y * WW + X;
        c0 = ld4(q); c1 = ld4(q + FRAME_PIX); c2 = ld4(q + 2 * FRAME_PIX);
    } else {
        c0 = make_float4(0.f, 0.f, 0.f, 0.f); c1 = c0; c2 = c0;
    }
}

#define FLOWJ_P(T, M, Bt, f0, f1, f2, g2v, uj, vj)                              \
    {                                                                           \
        const float Ix = ((T).f0 - (T).f2) + 2.0f * ((M).f0 - (M).f2)           \
                       + ((Bt).f0 - (Bt).f2);                                   \
        const float Iy = ((T).f0 + 2.0f * (T).f1 + (T).f2)                      \
                       - ((Bt).f0 + 2.0f * (Bt).f1 + (Bt).f2);                  \
        const float It = (g2v) - (M).f1;                                        \
        const float inv = 1.0f / (Ix * Ix + Iy * Iy + EPS);                     \
        uj = -(Ix * It) * inv;                                                  \
        vj = -(Iy * It) * inv;                                                  \
    }

#define FLOWJ_G(T, M, Bt, f0, f1, f2, g2v, uj, vj, mmv)                         \
    {                                                                           \
        const float Ix = ((T).f0 - (T).f2) + 2.0f * ((M).f0 - (M).f2)           \
                       + ((Bt).f0 - (Bt).f2);                                   \
        const float Iy = ((T).f0 + 2.0f * (T).f1 + (T).f2)                      \
                       - ((Bt).f0 + 2.0f * (Bt).f1 + (Bt).f2);                  \
        const float It = (g2v) - (M).f1;                                        \
        const float inv = 1.0f / (Ix * Ix + Iy * Iy + EPS);                     \
        s += (fabsf((uj) + (Ix * It) * inv) + fabsf((vj) + (Iy * It) * inv))    \
             * (mmv);                                                           \
    }

// One output row ROWY. Software-pipelined: consumes the bottom row (ROWY+1)
// of p1/g1 PREFETCHED by the previous step (fb* regs), issues this step's
// center loads (p2/g2 row ROWY) FIRST and the next step's bottom prefetch
// (row ROWY+2) SECOND, so ~12 float4 stay in flight through the compute
// phase (round-7 version held zero outstanding bytes during compute ->
// 1.6 TB/s, latency-bound). Param named ROWY (preprocessor would rewrite
// .y field accesses if named 'y').
#define STEP(ROWY, DO_PF)                                                       \
    {                                                                           \
        float4 pc0, pc1, pc2, gc0, gc1, gc2;                                    \
        ld3(p2, (ROWY), X, pc0, pc1, pc2);                                      \
        ld3(g2, (ROWY), X, gc0, gc1, gc2);                                      \
        float4 nbp0, nbp1, nbp2, nbg0, nbg1, nbg2;                              \
        if (DO_PF) {                                                            \
            ld3(p1, (ROWY) + 2, X, nbp0, nbp1, nbp2);                           \
            ld3(g1, (ROWY) + 2, X, nbg0, nbg1, nbg2);                           \
        } else {                                                                \
            nbp0 = make_float4(0.f, 0.f, 0.f, 0.f); nbp1 = nbp0; nbp2 = nbp0;   \
            nbg0 = nbp0; nbg1 = nbp0; nbg2 = nbp0;                              \
        }                                                                       \
        const GRow pB = mk_grow(gray4(fbp0, fbp1, fbp2), lane);                 \
        const GRow gB = mk_grow(gray4(fbg0, fbg1, fbg2), lane);                 \
        const float mm0 = (fabsf(gc0.x - k0.x) + fabsf(gc1.x - k1.x)            \
                         + fabsf(gc2.x - k2.x)) * (1.f / 3.f);                  \
        const float mm1 = (fabsf(gc0.y - k0.y) + fabsf(gc1.y - k1.y)            \
                         + fabsf(gc2.y - k2.y)) * (1.f / 3.f);                  \
        const float mm2 = (fabsf(gc0.z - k0.z) + fabsf(gc1.z - k1.z)            \
                         + fabsf(gc2.z - k2.z)) * (1.f / 3.f);                  \
        const float mm3 = (fabsf(gc0.w - k0.w) + fabsf(gc1.w - k1.w)            \
                         + fabsf(gc2.w - k2.w)) * (1.f / 3.f);                  \
        const float4 gp2c = gray4(pc0, pc1, pc2);                               \
        const float4 gg2c = gray4(gc0, gc1, gc2);                               \
        float u0, u1, u2, u3, v0, v1, v2, v3;                                   \
        FLOWJ_P(pT, pM, pB, l, a, b, gp2c.x, u0, v0)                            \
        FLOWJ_P(pT, pM, pB, a, b, c, gp2c.y, u1, v1)                            \
        FLOWJ_P(pT, pM, pB, b, c, d, gp2c.z, u2, v2)                            \
        FLOWJ_P(pT, pM, pB, c, d, r, gp2c.w, u3, v3)                            \
        FLOWJ_G(gT, gM, gB, l, a, b, gg2c.x, u0, v0, mm0)                       \
        FLOWJ_G(gT, gM, gB, a, b, c, gg2c.y, u1, v1, mm1)                       \
        FLOWJ_G(gT, gM, gB, b, c, d, gg2c.z, u2, v2, mm2)                       \
        FLOWJ_G(gT, gM, gB, c, d, r, gg2c.w, u3, v3, mm3)                       \
        pT = pM; pM = pB;                                                       \
        gT = gM; gM = gB;                                                       \
        k0 = fbg0; k1 = fbg1; k2 = fbg2;                                        \
        fbp0 = nbp0; fbp1 = nbp1; fbp2 = nbp2;                                  \
        fbg0 = nbg0; fbg1 = nbg1; fbg2 = nbg2;                                  \
    }

// Barrier-free flow loss: one WAVE per (batch, pair, 4-row strip), 128-thread
// blocks (1792 blocks = even 7/CU). Zero LDS/syncthreads; 1-deep load
// prefetch keeps the memory pipe fed through compute.
// __launch_bounds__(128, 3): VGPR cap 170, est. live ~150 -> 12 waves/CU.
__global__ __launch_bounds__(128, 3) void flow_loss_kernel(
    const float* __restrict__ pred, const float* __restrict__ gt,
    float* __restrict__ partial)
{
    const int tid   = threadIdx.x;
    const int lane  = tid & 63;
    const int item  = blockIdx.x * 2 + (tid >> 6);   // 0..3583
    const int strip = item & (NSTRIP - 1);
    const int pbt   = item >> 6;                     // 0..55
    const int b     = pbt / NPAIR;
    const int t     = pbt - b * NPAIR;

    const size_t fs = (size_t)3 * FRAME_PIX;
    const float* p1 = pred + ((size_t)b * TT + t) * fs;
    const float* g1 = gt   + ((size_t)b * TT + t) * fs;
    const float* p2 = p1 + fs;
    const float* g2 = g1 + fs;

    const int X  = lane * 4;
    const int y0 = strip * RROWS;

    GRow pT, pM, gT, gM;            // rolling gray rows (top, mid) pred/gt
    float4 k0, k1, k2;              // raw gt(t) channels of current output row
    float4 fbp0, fbp1, fbp2, fbg0, fbg1, fbg2;   // prefetched bottom row (p1/g1)

    // ---- prologue: rows y0-1 (top), y0 (mid), prefetch y0+1 (bottom) ----
    {
        float4 a0, a1, a2, c0, c1, c2;
        ld3(p1, y0 - 1, X, a0, a1, a2);
        ld3(g1, y0 - 1, X, c0, c1, c2);
        ld3(p1, y0, X, fbp0, fbp1, fbp2);        // reuse fb regs briefly
        ld3(g1, y0, X, k0, k1, k2);
        pT = mk_grow(gray4(a0, a1, a2), lane);
        gT = mk_grow(gray4(c0, c1, c2), lane);
        pM = mk_grow(gray4(fbp0, fbp1, fbp2), lane);
        gM = mk_grow(gray4(k0, k1, k2), lane);
        ld3(p1, y0 + 1, X, fbp0, fbp1, fbp2);    // bottom prefetch for STEP 0
        ld3(g1, y0 + 1, X, fbg0, fbg1, fbg2);
    }

    float s = 0.f;
    STEP(y0, 1)
    STEP(y0 + 1, 1)
    STEP(y0 + 2, 1)
    STEP(y0 + 3, 0)

    // ---- wave reduction -> one partial per wave-item (no barrier) ----
    #pragma unroll
    for (int off = 32; off > 0; off >>= 1) s += __shfl_down(s, off, 64);
    if (lane == 0) partial[item] = s;
}

__global__ __launch_bounds__(896) void reduce_kernel(
    const float* __restrict__ partial, float* __restrict__ out)
{
    const float4 v = ld4(partial + threadIdx.x * 4);   // 3584 floats total
    float s = (v.x + v.y) + (v.z + v.w);
    #pragma unroll
    for (int off = 32; off > 0; off >>= 1) s += __shfl_down(s, off, 64);

    __shared__ float wsum[14];
    if ((threadIdx.x & 63) == 0) wsum[threadIdx.x >> 6] = s;
    __syncthreads();
    if (threadIdx.x == 0) {
        float tot = 0.f;
        #pragma unroll
        for (int i = 0; i < 14; ++i) tot += wsum[i];
        out[0] = tot * INV_N;
    }
}

extern "C" void kernel_launch(void* const* d_in, const int* in_sizes, int n_in,
                              void* d_out, int out_size, void* d_ws, size_t ws_size,
                              hipStream_t stream) {
    const float* pred = (const float*)d_in[0];
    const float* gt   = (const float*)d_in[1];
    float* partial    = (float*)d_ws;     // NITEM floats = 14336 B
    float* out        = (float*)d_out;

    flow_loss_kernel<<<dim3(NBLK), dim3(128), 0, stream>>>(pred, gt, partial);
    reduce_kernel<<<1, 896, 0, stream>>>(partial, out);
}

// Round 12
// 121.457 us; speedup vs baseline: 1.4070x; 1.4070x over previous
//
#include <hip/hip_runtime.h>

// Frames [B, T, C, H, W] = [8, 8, 3, 256, 256] fp32
// Base: round-2 kernel (known-green, harness 119.2us) with ONE minimal
// diff: XCD-locality remap of (b, t, tile). 3-D grid (64,7,8) dispatch
// linearizes x-major, so linear%8 == blockIdx.x%8 == XCD under
// round-robin; b = blockIdx.x&7 pins each batch to one XCD. Remaining
// bits re-derive the tile: tile = (x>>3)|(z<<3), t = y (bijective).
// Per-pair working set (frames t,t+1 of pred+gt = 3MB) fits the 4MB
// per-XCD L2; frame t+1 is reused by pair t+1 -> L2 hits (~200cy)
// instead of cold HBM (~900cy).
#define BB 8
#define TT 8
#define NPAIR (TT - 1)               // 7
#define HH 256
#define WW 256
#define FRAME_PIX (HH * WW)
#define XW 128                       // tile width
#define RROWS 8                      // tile rows
#define NYT (HH / RROWS)             // 32
#define NXT (WW / XW)                // 2
#define PADW 136                     // 4 pad + 128 + 4 pad floats
#define NBLK (NYT * NXT * NPAIR * BB) // 3584 blocks
#define EPS 1e-3f
#define INV_N (1.0f / (float)((size_t)BB * NPAIR * 2 * HH * WW))

__device__ __forceinline__ float4 ld4(const float* __restrict__ p) {
    return *reinterpret_cast<const float4*>(p);
}
__device__ __forceinline__ void st4(float* p, const float4 v) {
    *reinterpret_cast<float4*>(p) = v;
}
__device__ __forceinline__ float4 gray4(const float4 r, const float4 g, const float4 b) {
    float4 o;
    o.x = 0.2989f * r.x + 0.587f * g.x + 0.114f * b.x;
    o.y = 0.2989f * r.y + 0.587f * g.y + 0.114f * b.y;
    o.z = 0.2989f * r.z + 0.587f * g.z + 0.114f * b.z;
    o.w = 0.2989f * r.w + 0.587f * g.w + 0.114f * b.w;
    return o;
}

// One block per (batch, pair, 128x8 tile). All global loads issued up-front
// with no dependent chain; single barrier for the gray(t)->LDS handoff.
// __launch_bounds__(256, 3): VGPR cap ~168, no scratch spill.
__global__ __launch_bounds__(256, 3) void flow_loss_kernel(
    const float* __restrict__ pred, const float* __restrict__ gt,
    float* __restrict__ partial)
{
    __shared__ float gbuf[2][RROWS + 2][PADW];   // 10880 B; row 0 = y0-1

    // ---- XCD-locality remap (the only diff vs the green round-2 body) ----
    const int b    = blockIdx.x & 7;                          // XCD id
    const int tile = (blockIdx.x >> 3) | (blockIdx.z << 3);   // 0..63
    const int t    = blockIdx.y;                              // 0..6
    const int ytile = tile >> 1;
    const int xtile = tile & 1;

    const int y0    = ytile * RROWS;
    const int x0    = xtile * XW;
    const int tid   = threadIdx.x;
    const size_t fs = (size_t)3 * FRAME_PIX;
    const float* p1 = pred + ((size_t)b * TT + t) * fs;
    const float* g1 = gt   + ((size_t)b * TT + t) * fs;
    const float* p2 = p1 + fs;
    const float* g2 = g1 + fs;

    // compute mapping: row r (0..7), 4 px at col cx (0..124)
    const int r  = tid >> 5;
    const int cx = (tid & 31) * 4;
    const size_t coff = (size_t)(y0 + r) * WW + (x0 + cx);

    // "extra" staging role for frame-t halo: tid<128 -> halo rows;
    // 128..167 -> side pads (both images)
    bool e_act = false, e_val = false;
    int  e_img = 0;
    size_t e_off = 0;
    float* e_dst = &gbuf[0][0][0];
    if (tid < 128) {
        e_act = true;
        e_img = tid >> 6;
        const int rsel = (tid >> 5) & 1;
        const int ec   = (tid & 31) * 4;
        const int ey   = rsel ? (y0 + RROWS) : (y0 - 1);
        e_val = (unsigned)ey < HH;
        e_off = e_val ? ((size_t)ey * WW + x0 + ec) : 0;
        e_dst = &gbuf[e_img][rsel ? RROWS + 1 : 0][4 + ec];
    } else if (tid < 168) {
        const int j = tid - 128;
        e_act = true;
        e_img = j / 20;
        const int rem  = j % 20;
        const int side = rem / 10;
        const int prow = rem % 10;
        const int ey = y0 - 1 + prow;
        const int ex = side ? (x0 + XW) : (x0 - 4);
        e_val = ((unsigned)ey < HH) && ((unsigned)ex < WW);
        e_off = e_val ? ((size_t)ey * WW + ex) : 0;
        e_dst = &gbuf[e_img][prow][side ? 4 + XW : 0];
    }

    // ---- issue ALL global loads up front (independent, deep MLP) ----
    const float4 a1r = ld4(p1 + coff);
    const float4 a1g = ld4(p1 + coff + FRAME_PIX);
    const float4 a1b = ld4(p1 + coff + 2 * FRAME_PIX);
    const float4 b1r = ld4(g1 + coff);
    const float4 b1g = ld4(g1 + coff + FRAME_PIX);
    const float4 b1b = ld4(g1 + coff + 2 * FRAME_PIX);
    const float4 a2r = ld4(p2 + coff);
    const float4 a2g = ld4(p2 + coff + FRAME_PIX);
    const float4 a2b = ld4(p2 + coff + 2 * FRAME_PIX);
    const float4 b2r = ld4(g2 + coff);
    const float4 b2g = ld4(g2 + coff + FRAME_PIX);
    const float4 b2b = ld4(g2 + coff + 2 * FRAME_PIX);
    float4 e0 = make_float4(0.f, 0.f, 0.f, 0.f), e1 = e0, e2 = e0;
    if (e_act && e_val) {
        const float* eb = e_img ? g1 : p1;
        e0 = ld4(eb + e_off);
        e1 = ld4(eb + e_off + FRAME_PIX);
        e2 = ld4(eb + e_off + 2 * FRAME_PIX);
    }

    // ---- gray(t) -> LDS (center + halo) ----
    st4(&gbuf[0][r + 1][4 + cx], gray4(a1r, a1g, a1b));
    st4(&gbuf[1][r + 1][4 + cx], gray4(b1r, b1g, b1b));
    if (e_act) st4(e_dst, gray4(e0, e1, e2));

    // motion mag for this pair (gt frames t, t+1; mean over channels)
    float mm[4];
    mm[0] = (fabsf(b2r.x - b1r.x) + fabsf(b2g.x - b1g.x) + fabsf(b2b.x - b1b.x)) * (1.f / 3.f);
    mm[1] = (fabsf(b2r.y - b1r.y) + fabsf(b2g.y - b1g.y) + fabsf(b2b.y - b1b.y)) * (1.f / 3.f);
    mm[2] = (fabsf(b2r.z - b1r.z) + fabsf(b2g.z - b1g.z) + fabsf(b2b.z - b1b.z)) * (1.f / 3.f);
    mm[3] = (fabsf(b2r.w - b1r.w) + fabsf(b2g.w - b1g.w) + fabsf(b2b.w - b1b.w)) * (1.f / 3.f);

    // gray(t+1) stays in regs (center only; It and mm need no halo)
    const float4 gp2 = gray4(a2r, a2g, a2b);
    const float4 gg2 = gray4(b2r, b2g, b2b);

    __syncthreads();

    // ---- Sobel on gray(t) from LDS, It vs gray(t+1) in regs ----
    float s = 0.f;
    float up[4], vp[4];
    #pragma unroll
    for (int img = 0; img < 2; ++img) {
        // padded floats cx+3..cx+8 -> aligned float4s at cx, cx+4, cx+8
        float w0[6], w1[6], w2[6];
        {
            const float* p = &gbuf[img][r][cx];
            const float4 A = ld4(p), B = ld4(p + 4), C = ld4(p + 8);
            w0[0] = A.w; w0[1] = B.x; w0[2] = B.y; w0[3] = B.z; w0[4] = B.w; w0[5] = C.x;
        }
        {
            const float* p = &gbuf[img][r + 1][cx];
            const float4 A = ld4(p), B = ld4(p + 4), C = ld4(p + 8);
            w1[0] = A.w; w1[1] = B.x; w1[2] = B.y; w1[3] = B.z; w1[4] = B.w; w1[5] = C.x;
        }
        {
            const float* p = &gbuf[img][r + 2][cx];
            const float4 A = ld4(p), B = ld4(p + 4), C = ld4(p + 8);
            w2[0] = A.w; w2[1] = B.x; w2[2] = B.y; w2[3] = B.z; w2[4] = B.w; w2[5] = C.x;
        }
        const float4 gr2 = img ? gg2 : gp2;
        const float g2a[4] = {gr2.x, gr2.y, gr2.z, gr2.w};
        #pragma unroll
        for (int j = 0; j < 4; ++j) {
            const float Ix = (w0[j] - w0[j + 2]) + 2.0f * (w1[j] - w1[j + 2]) + (w2[j] - w2[j + 2]);
            const float Iy = (w0[j] + 2.0f * w0[j + 1] + w0[j + 2])
                           - (w2[j] + 2.0f * w2[j + 1] + w2[j + 2]);
            const float It = g2a[j] - w1[j + 1];
            const float inv = 1.0f / (Ix * Ix + Iy * Iy + EPS);
            if (img == 0) {
                up[j] = -(Ix * It) * inv;
                vp[j] = -(Iy * It) * inv;
            } else {
                s += (fabsf(up[j] + (Ix * It) * inv) + fabsf(vp[j] + (Iy * It) * inv)) * mm[j];
            }
        }
    }

    // ---- Block reduction -> one partial per block ----
    #pragma unroll
    for (int off = 32; off > 0; off >>= 1) s += __shfl_down(s, off, 64);

    __shared__ float wsum[4];
    if ((tid & 63) == 0) wsum[tid >> 6] = s;
    __syncthreads();
    if (tid == 0) {
        partial[((b * NPAIR) + t) * (NYT * NXT) + tile] =
            wsum[0] + wsum[1] + wsum[2] + wsum[3];
    }
}

__global__ __launch_bounds__(896) void reduce_kernel(
    const float* __restrict__ partial, float* __restrict__ out)
{
    const float4 v = ld4(partial + threadIdx.x * 4);   // 3584 floats total
    float s = (v.x + v.y) + (v.z + v.w);
    #pragma unroll
    for (int off = 32; off > 0; off >>= 1) s += __shfl_down(s, off, 64);

    __shared__ float wsum[14];
    if ((threadIdx.x & 63) == 0) wsum[threadIdx.x >> 6] = s;
    __syncthreads();
    if (threadIdx.x == 0) {
        float tot = 0.f;
        #pragma unroll
        for (int i = 0; i < 14; ++i) tot += wsum[i];
        out[0] = tot * INV_N;
    }
}

extern "C" void kernel_launch(void* const* d_in, const int* in_sizes, int n_in,
                              void* d_out, int out_size, void* d_ws, size_t ws_size,
                              hipStream_t stream) {
    const float* pred = (const float*)d_in[0];
    const float* gt   = (const float*)d_in[1];
    float* partial    = (float*)d_ws;     // NBLK floats = 14336 B
    float* out        = (float*)d_out;

    dim3 grid(NYT * NXT, NPAIR, BB);      // (64, 7, 8) = 3584 blocks
    dim3 block(256);
    flow_loss_kernel<<<grid, block, 0, stream>>>(pred, gt, partial);
    reduce_kernel<<<1, 896, 0, stream>>>(partial, out);
}